// Round 1
// baseline (36.837 us; speedup 1.0000x reference)
//
#include <hip/hip_runtime.h>
#include <math.h>

// Problem constants (from setup_inputs): B=32, S=1024, D=256, V=50000.
// loss(b,s) = -logcmk(256, k) - 0.1*dot + 0.02*k,  k = ||preds[b,:,s]||
// logcmk(m,k) = v*log k - (logIv(k) - k) - (m/2) log(2pi),  v = 127
// => loss = -127*log k + logIv - k + 128*log(2pi) - 0.1*dot + 0.02*k
// logIv via 64-term series: T_j = (2j+127)*log(k/2) - lgamma(j+1) - lgamma(128+j),
// logIv = logsumexp_j T_j.   Output: sum(loss*mask)/sum(mask), mask = (target != 1).

constexpr int Dc = 256;
constexpr int Sc = 1024;
constexpr int Bc = 32;
constexpr int TILE = 64;                 // positions per block
constexpr int NBLK = Bc * Sc / TILE;     // 512

__global__ __launch_bounds__(256) void nllvmf_main(
    const float* __restrict__ preds,
    const float* __restrict__ emb,
    const int*   __restrict__ target,
    float*       __restrict__ ws)        // ws[0] = sum(loss*mask), ws[1] = sum(mask)
{
    __shared__ float sA[64];             // lgamma(j+1) + lgamma(128+j)
    __shared__ float s_n[16][64];
    __shared__ float s_d[16][64];

    const int tid = threadIdx.x;
    if (tid < 64) {
        float j = (float)tid;
        sA[tid] = lgammaf(j + 1.0f) + lgammaf(128.0f + j);
    }

    const int blk = blockIdx.x;
    const int b   = blk >> 4;            // blk / (Sc/TILE)
    const int s0  = (blk & 15) * TILE;
    const int sg  = tid & 15;            // s-group: positions p0 .. p0+3
    const int td  = tid >> 4;            // d-chunk 0..15 (16 dims each)
    const int p0  = s0 + sg * 4;

    const float* pb = preds + (size_t)b * Dc * Sc + p0;
    const float* eb[4];
    #pragma unroll
    for (int j = 0; j < 4; ++j) {
        int t = target[b * Sc + p0 + j];
        eb[j] = emb + (size_t)t * Dc;
    }

    float n2[4] = {0.f, 0.f, 0.f, 0.f};
    float dt[4] = {0.f, 0.f, 0.f, 0.f};
    const int d0 = td * 16;

    #pragma unroll
    for (int ii = 0; ii < 4; ++ii) {
        float e[4][4];
        #pragma unroll
        for (int j = 0; j < 4; ++j) {
            float4 v = *reinterpret_cast<const float4*>(eb[j] + d0 + ii * 4);
            e[j][0] = v.x; e[j][1] = v.y; e[j][2] = v.z; e[j][3] = v.w;
        }
        #pragma unroll
        for (int q = 0; q < 4; ++q) {
            const int d = d0 + ii * 4 + q;
            float4 p = *reinterpret_cast<const float4*>(pb + (size_t)d * Sc);
            float pv[4] = {p.x, p.y, p.z, p.w};
            #pragma unroll
            for (int j = 0; j < 4; ++j) {
                n2[j] = fmaf(pv[j], pv[j], n2[j]);
                dt[j] = fmaf(pv[j], e[j][q], dt[j]);
            }
        }
    }

    #pragma unroll
    for (int j = 0; j < 4; ++j) {
        s_n[td][sg * 4 + j] = n2[j];
        s_d[td][sg * 4 + j] = dt[j];
    }
    __syncthreads();

    if (tid < 64) {
        float norm2 = 0.f, dot = 0.f;
        #pragma unroll
        for (int t = 0; t < 16; ++t) {
            norm2 += s_n[t][tid];
            dot   += s_d[t][tid];
        }
        const int tgt = target[b * Sc + s0 + tid];
        const float k   = sqrtf(norm2);
        const float lhk = logf(0.5f * k);

        float mx = -1e30f;
        #pragma unroll 8
        for (int j = 0; j < 64; ++j)
            mx = fmaxf(mx, fmaf(2.0f * j + 127.0f, lhk, -sA[j]));
        float ssum = 0.f;
        #pragma unroll 8
        for (int j = 0; j < 64; ++j)
            ssum += __expf(fmaf(2.0f * j + 127.0f, lhk, -sA[j]) - mx);
        const float logIv = mx + __logf(ssum);

        float loss = fmaf(-127.0f, logf(k), logIv) - k + 235.2482645003962f
                   - 0.1f * dot + 0.02f * k;
        float msk = (tgt != 1) ? 1.0f : 0.0f;
        loss *= msk;

        #pragma unroll
        for (int off = 32; off; off >>= 1) {
            loss += __shfl_down(loss, off, 64);
            msk  += __shfl_down(msk,  off, 64);
        }
        if (tid == 0) {
            atomicAdd(&ws[0], loss);
            atomicAdd(&ws[1], msk);
        }
    }
}

__global__ void nllvmf_finalize(const float* __restrict__ ws,
                                float* __restrict__ out)
{
    out[0] = ws[0] / ws[1];
}

extern "C" void kernel_launch(void* const* d_in, const int* in_sizes, int n_in,
                              void* d_out, int out_size, void* d_ws, size_t ws_size,
                              hipStream_t stream) {
    const float* preds  = (const float*)d_in[0];
    const float* emb    = (const float*)d_in[1];
    const int*   target = (const int*)d_in[2];
    float* out = (float*)d_out;
    float* ws  = (float*)d_ws;

    hipMemsetAsync(ws, 0, 2 * sizeof(float), stream);
    nllvmf_main<<<NBLK, 256, 0, stream>>>(preds, emb, target, ws);
    nllvmf_finalize<<<1, 1, 0, stream>>>(ws, out);
}

// Round 2
// 30.994 us; speedup vs baseline: 1.1885x; 1.1885x over previous
//
#include <hip/hip_runtime.h>
#include <math.h>

// B=32, S=1024, D=256, V=50000.
// loss(b,s) = -127*log k + logIv(k) - k + 128*log(2pi) - 0.1*dot + 0.02*k
//   k = ||preds[b,:,s]||, dot = <emb[target], preds[b,:,s]>
// logIv = logsumexp_j [(2j+127)*log(k/2) - lgamma(j+1) - lgamma(128+j)], j<64
// out = sum(loss*mask)/sum(mask), mask = target != 1.

constexpr int Dc = 256;
constexpr int Sc = 1024;
constexpr int Bc = 32;
constexpr int TILE = 16;                  // positions per block
constexpr int NBLK = Bc * Sc / TILE;      // 2048

__global__ __launch_bounds__(256) void nllvmf_main(
    const float* __restrict__ preds,
    const float* __restrict__ emb,
    const int*   __restrict__ target,
    float*       __restrict__ partial)    // [0..NBLK): loss, [NBLK..2*NBLK): mask
{
    __shared__ float sA[64];              // lgamma(j+1) + lgamma(128+j)
    __shared__ float s_r[4][2][16];       // [wave][n2|dot][pos]

    const int tid = threadIdx.x;
    if (tid < 64) {
        float j = (float)tid;
        sA[tid] = lgammaf(j + 1.0f) + lgammaf(128.0f + j);
    }

    const int blk = blockIdx.x;
    const int b   = blk >> 6;             // Sc/TILE = 64 blocks per batch row
    const int s0  = (blk & 63) * TILE;
    const int w   = tid >> 6;             // wave 0..3: dim slice w*64..w*64+63
    const int l   = tid & 63;
    const int td  = l >> 2;               // 16 d-chunks of 4 dims
    const int sg  = l & 3;                // 4 position-groups of 4
    const int d0  = w * 64 + td * 4;
    const int p0  = s0 + sg * 4;

    // targets for this thread's 4 positions (same 64B line per sg-group)
    const int* tb = target + b * Sc + p0;
    int tg[4];
    #pragma unroll
    for (int j = 0; j < 4; ++j) tg[j] = tb[j];

    // 4 independent emb float4 loads (gather) + 4 coalesced preds float4 loads
    float e[4][4];
    #pragma unroll
    for (int j = 0; j < 4; ++j) {
        float4 v = *reinterpret_cast<const float4*>(emb + (size_t)tg[j] * Dc + d0);
        e[j][0] = v.x; e[j][1] = v.y; e[j][2] = v.z; e[j][3] = v.w;
    }
    const float* pb = preds + (size_t)b * Dc * Sc + (size_t)d0 * Sc + p0;
    float pq[4][4];
    #pragma unroll
    for (int q = 0; q < 4; ++q) {
        float4 p = *reinterpret_cast<const float4*>(pb + (size_t)q * Sc);
        pq[q][0] = p.x; pq[q][1] = p.y; pq[q][2] = p.z; pq[q][3] = p.w;
    }

    float n2[4] = {0.f,0.f,0.f,0.f};
    float dt[4] = {0.f,0.f,0.f,0.f};
    #pragma unroll
    for (int q = 0; q < 4; ++q)
        #pragma unroll
        for (int j = 0; j < 4; ++j) {
            n2[j] = fmaf(pq[q][j], pq[q][j], n2[j]);
            dt[j] = fmaf(pq[q][j], e[j][q], dt[j]);
        }

    // reduce over td (lane bits 2..5): after this every lane holds its
    // sg-group's 4 positions summed over this wave's 64 dims
    #pragma unroll
    for (int m = 4; m <= 32; m <<= 1)
        #pragma unroll
        for (int j = 0; j < 4; ++j) {
            n2[j] += __shfl_xor(n2[j], m, 64);
            dt[j] += __shfl_xor(dt[j], m, 64);
        }

    if (td == 0) {
        #pragma unroll
        for (int j = 0; j < 4; ++j) {
            s_r[w][0][sg * 4 + j] = n2[j];
            s_r[w][1][sg * 4 + j] = dt[j];
        }
    }
    __syncthreads();

    if (tid < 16) {
        float norm2 = s_r[0][0][tid] + s_r[1][0][tid] + s_r[2][0][tid] + s_r[3][0][tid];
        float dot   = s_r[0][1][tid] + s_r[1][1][tid] + s_r[2][1][tid] + s_r[3][1][tid];
        const int tgt = target[b * Sc + s0 + tid];

        const float k   = sqrtf(norm2);
        const float lhk = __logf(0.5f * k);

        float mx = -1e30f;
        #pragma unroll 8
        for (int j = 0; j < 64; ++j)
            mx = fmaxf(mx, fmaf(2.0f * j + 127.0f, lhk, -sA[j]));
        float ssum = 0.f;
        #pragma unroll 8
        for (int j = 0; j < 64; ++j)
            ssum += __expf(fmaf(2.0f * j + 127.0f, lhk, -sA[j]) - mx);
        const float logIv = mx + __logf(ssum);

        float loss = fmaf(-127.0f, __logf(k), logIv) - k + 235.2482645003962f
                   - 0.1f * dot + 0.02f * k;
        float msk = (tgt != 1) ? 1.0f : 0.0f;
        loss *= msk;

        #pragma unroll
        for (int off = 8; off; off >>= 1) {
            loss += __shfl_down(loss, off, 64);
            msk  += __shfl_down(msk,  off, 64);
        }
        if (tid == 0) {
            partial[blk]        = loss;
            partial[NBLK + blk] = msk;
        }
    }
}

__global__ __launch_bounds__(256) void nllvmf_finalize(
    const float* __restrict__ partial, float* __restrict__ out)
{
    __shared__ float sl[4], sm[4];
    const int tid = threadIdx.x;
    float l = 0.f, m = 0.f;
    for (int i = tid; i < NBLK; i += 256) {
        l += partial[i];
        m += partial[NBLK + i];
    }
    #pragma unroll
    for (int off = 32; off; off >>= 1) {
        l += __shfl_down(l, off, 64);
        m += __shfl_down(m, off, 64);
    }
    if ((tid & 63) == 0) { sl[tid >> 6] = l; sm[tid >> 6] = m; }
    __syncthreads();
    if (tid == 0)
        out[0] = (sl[0] + sl[1] + sl[2] + sl[3]) / (sm[0] + sm[1] + sm[2] + sm[3]);
}

extern "C" void kernel_launch(void* const* d_in, const int* in_sizes, int n_in,
                              void* d_out, int out_size, void* d_ws, size_t ws_size,
                              hipStream_t stream) {
    const float* preds  = (const float*)d_in[0];
    const float* emb    = (const float*)d_in[1];
    const int*   target = (const int*)d_in[2];
    float* out = (float*)d_out;
    float* ws  = (float*)d_ws;

    nllvmf_main<<<NBLK, 256, 0, stream>>>(preds, emb, target, ws);
    nllvmf_finalize<<<1, 256, 0, stream>>>(ws, out);
}